// Round 2
// baseline (300.206 us; speedup 1.0000x reference)
//
#include <hip/hip_runtime.h>

// TaylorExp feature map, d=16:
//   out[row, 0]             = 1
//   out[row, 1..16]         = x[row, i] * 0.5                     (1/rrd)
//   out[row, 17 + i*16 + j] = x[row,i]*x[row,j] * (1/(4*sqrt(2)))
//
// Write-bound: 286 MB out vs 16.8 MB in -> floor ~48 us at 6.3 TB/s.
// Two-phase design: phase 1 computes the block's whole output chunk into LDS
// (branch-free), phase 2 streams LDS -> global as aligned b128/dwordx4 copies
// with no divides/branches in the hot loop.

#define D               16
#define OUTD            273          // 1 + 16 + 256
#define ROWS_PER_BLOCK  16
#define THREADS         256
#define CHUNK           (OUTD * ROWS_PER_BLOCK)   // 4368 floats
#define CHUNK4          (CHUNK / 4)               // 1092 float4
#define TAIL4           (CHUNK4 - 4 * THREADS)    // 68

__global__ __launch_bounds__(THREADS)
void taylor_exp_kernel(const float* __restrict__ x,
                       float* __restrict__ out,
                       int nrows) {
    __shared__ float xs[ROWS_PER_BLOCK * D];            // 1 KB input tile
    __shared__ __align__(16) float ybuf[CHUNK];         // 17472 B output tile

    const int tid = threadIdx.x;
    const long long rowBase = (long long)blockIdx.x * ROWS_PER_BLOCK;

    // ---- Phase 0: stage 16 rows x 16 floats (one coalesced 1 KB load) ----
    {
        const int localRow = tid >> 4;
        float v = 0.0f;
        if (rowBase + localRow < (long long)nrows) {
            v = x[rowBase * D + tid];
        }
        xs[tid] = v;
    }
    __syncthreads();

    // ---- Phase 1: compute chunk into LDS, branch-free ----
    // thread tid = (r, j): r = row in block, j = column of the outer product.
    // Writes column j of row r's 16x16 quadratic tile + linear element j.
    {
        const int r = tid >> 4;        // 0..15
        const int j = tid & 15;        // 0..15
        const float S2 = 0.17677669529663688f;   // 1/(4*sqrt(2))
        const float xj = xs[r * D + j];
        float* yrow = &ybuf[r * OUTD];

        yrow[1 + j] = xj * 0.5f;       // linear term
        if (j == 0) yrow[0] = 1.0f;    // constant term

        const float xjs = xj * S2;
#pragma unroll
        for (int i = 0; i < D; ++i) {
            // addresses across the wave: (17r + 17 + 16i + j) mod 32
            // -> <=2-3 lanes/bank, effectively conflict-free
            yrow[17 + i * 16 + j] = xs[r * D + i] * xjs;
        }
    }
    __syncthreads();

    // ---- Phase 2: pure streaming copy LDS -> global (aligned float4) ----
    const long long outBase = rowBase * OUTD;            // multiple of 4368
    const long long totalOut = (long long)nrows * OUTD;
    const float4* ysrc = reinterpret_cast<const float4*>(ybuf);

    if (outBase + CHUNK <= totalOut) {
        float4* dst = reinterpret_cast<float4*>(out + outBase);
#pragma unroll
        for (int k = 0; k < 4; ++k) {
            dst[tid + k * THREADS] = ysrc[tid + k * THREADS];
        }
        if (tid < TAIL4) {
            dst[tid + 4 * THREADS] = ysrc[tid + 4 * THREADS];
        }
    } else {
        // ragged last block (not hit when nrows % 16 == 0)
        for (int t = tid; t < CHUNK4; t += THREADS) {
            const long long gi = outBase + 4ll * t;
            float4 v = ysrc[t];
            if (gi + 4 <= totalOut) {
                *reinterpret_cast<float4*>(out + gi) = v;
            } else {
                const float vv[4] = {v.x, v.y, v.z, v.w};
                for (int e = 0; e < 4; ++e) {
                    if (gi + e < totalOut) out[gi + e] = vv[e];
                }
            }
        }
    }
}

extern "C" void kernel_launch(void* const* d_in, const int* in_sizes, int n_in,
                              void* d_out, int out_size, void* d_ws, size_t ws_size,
                              hipStream_t stream) {
    const float* x = (const float*)d_in[0];
    float* out = (float*)d_out;

    const int n = in_sizes[0];        // total x elements
    const int nrows = n / D;          // 262144 for the bench shape
    const int blocks = (nrows + ROWS_PER_BLOCK - 1) / ROWS_PER_BLOCK;

    taylor_exp_kernel<<<dim3(blocks), dim3(THREADS), 0, stream>>>(x, out, nrows);
}

// Round 4
// 299.799 us; speedup vs baseline: 1.0014x; 1.0014x over previous
//
#include <hip/hip_runtime.h>

// TaylorExp feature map, d=16:
//   out[row, 0]             = 1
//   out[row, 1..16]         = x[row, i] * 0.5                     (1/rrd)
//   out[row, 17 + i*16 + j] = (x[row,i]*x[row,j]) * (1/(4*sqrt(2)))
//
// Write-bound: 286 MB out vs 16.8 MB in -> floor ~48 us at 6.3 TB/s.
// R3: barrier-free wave-autonomous design. Each wave owns 4 rows end-to-end:
// stage x slice -> compute 1092-float chunk into its private LDS slice ->
// stream to global as aligned nontemporal dwordx4. Same-wave LDS RAW needs
// only lgkmcnt waits (compiler-inserted), no s_barrier -> waves free-run.
// R3b: use native ext_vector float4 for nontemporal stores (HIP float4 is a
// class type the builtin rejects).

#define D               16
#define OUTD            273          // 1 + 16 + 256
#define ROWS_PER_WAVE   4
#define WAVES_PER_BLOCK 4
#define ROWS_PER_BLOCK  (ROWS_PER_WAVE * WAVES_PER_BLOCK)   // 16
#define THREADS         256
#define WCHUNK          (OUTD * ROWS_PER_WAVE)   // 1092 floats per wave
#define WCHUNK4         (WCHUNK / 4)             // 273 float4 per wave

typedef float vfloat4 __attribute__((ext_vector_type(4)));

__global__ __launch_bounds__(THREADS)
void taylor_exp_kernel(const float* __restrict__ x,
                       float* __restrict__ out,
                       int nrows) {
    // Per-wave private slices; no cross-wave sharing -> no barriers.
    __shared__ __align__(16) float ybuf[WAVES_PER_BLOCK][WCHUNK];  // 17472 B
    __shared__ float xs[THREADS];                                  // 1 KB

    const int tid  = threadIdx.x;
    const int wave = tid >> 6;
    const int lane = tid & 63;

    const long long blockRow = (long long)blockIdx.x * ROWS_PER_BLOCK;
    const long long waveRow  = blockRow + wave * ROWS_PER_WAVE;

    // ---- Stage this wave's 4 rows x 16 floats (256 B coalesced) ----
    {
        float v = 0.0f;
        if (waveRow + (lane >> 4) < (long long)nrows) {
            v = x[waveRow * D + lane];
        }
        xs[tid] = v;   // same-wave producer; consumers below are same wave
    }

    // ---- Compute chunk into this wave's LDS slice (no barrier) ----
    {
        const int r = lane >> 4;        // 0..3  (row within wave)
        const int j = lane & 15;        // 0..15 (column)
        const float S2 = 0.17677669529663688f;   // 1/(4*sqrt(2))
        const float* xw = &xs[wave * 64 + r * D];
        float* yrow = &ybuf[wave][r * OUTD];

        const float xj = xw[j];         // lgkmcnt-ordered after xs write
        yrow[1 + j] = xj * 0.5f;        // linear term
        if (j == 0) yrow[0] = 1.0f;     // constant term

#pragma unroll
        for (int i = 0; i < D; ++i) {
            // (xi*xj)*S2 left-to-right: bit-matches reference rounding
            yrow[17 + i * 16 + j] = xw[i] * xj * S2;
        }
    }

    // ---- Stream this wave's 4368 B slice -> global (aligned float4) ----
    const long long outBase  = waveRow * OUTD;   // multiple of 1092 -> 16B aligned
    const long long totalOut = (long long)nrows * OUTD;
    const vfloat4* ysrc = reinterpret_cast<const vfloat4*>(&ybuf[wave][0]);

    if (waveRow + ROWS_PER_WAVE <= (long long)nrows) {
        vfloat4* dst = reinterpret_cast<vfloat4*>(out + outBase);
#pragma unroll
        for (int k = 0; k < 4; ++k) {
            __builtin_nontemporal_store(ysrc[lane + k * 64], &dst[lane + k * 64]);
        }
        if (lane < (WCHUNK4 - 4 * 64)) {   // tail: 17 float4
            __builtin_nontemporal_store(ysrc[lane + 256], &dst[lane + 256]);
        }
    } else {
        // ragged last rows (not hit when nrows % 16 == 0)
        for (int t = lane; t < WCHUNK4; t += 64) {
            const long long gi = outBase + 4ll * t;
            vfloat4 v = ysrc[t];
            if (gi + 4 <= totalOut) {
                *reinterpret_cast<vfloat4*>(out + gi) = v;
            } else {
                for (int e = 0; e < 4; ++e) {
                    if (gi + e < totalOut) out[gi + e] = v[e];
                }
            }
        }
    }
}

extern "C" void kernel_launch(void* const* d_in, const int* in_sizes, int n_in,
                              void* d_out, int out_size, void* d_ws, size_t ws_size,
                              hipStream_t stream) {
    const float* x = (const float*)d_in[0];
    float* out = (float*)d_out;

    const int n = in_sizes[0];        // total x elements
    const int nrows = n / D;          // 262144 for the bench shape
    const int blocks = (nrows + ROWS_PER_BLOCK - 1) / ROWS_PER_BLOCK;

    taylor_exp_kernel<<<dim3(blocks), dim3(THREADS), 0, stream>>>(x, out, nrows);
}